// Round 4
// baseline (563.771 us; speedup 1.0000x reference)
//
#include <hip/hip_runtime.h>

#define B_   4
#define CIN  23
#define H_   256
#define W_   512
#define CO   64
#define HC   16                 // h-chunks (blocks along H)
#define NPART (B_ * W_ * CO)    // elements per h-chunk partial = 131072

typedef float f32x4 __attribute__((ext_vector_type(4)));

// ---------------------------------------------------------------------------
// Kernel A: 1x1 conv (23->64) + bias + relu, partial sum over a 16-h chunk.
// Grid (wq=8, hc=16, b=4) = 512 blocks x 256 thr (4 waves, 4 h each).
// msa is read exactly ONCE chip-wide. All 64 channels per block; weights via
// uniform s_load (scalar pipe). Cross-wave reduce in XOR-swizzled LDS.
// partial[hc][b][w][c] lives in d_out (overwritten later by pairs_kernel).
// ---------------------------------------------------------------------------
__global__ __launch_bounds__(256) void conv_partial_kernel(
    const float* __restrict__ msa,   // [B][CIN][H][W]
    const float* __restrict__ Wc,    // [CO][CIN]
    const float* __restrict__ bias,  // [CO]
    float* __restrict__ partial)     // [HC][B][W][CO]
{
    const int tid  = threadIdx.x;
    const int lane = tid & 63;
    const int wv   = tid >> 6;            // 0..3
    const int wq   = blockIdx.x;          // 0..7
    const int hc   = blockIdx.y;          // 0..15
    const int b    = blockIdx.z;
    const int w    = wq * 64 + lane;
    const int h0   = hc * 16 + wv * 4;

    float acc[CO];
#pragma unroll
    for (int c = 0; c < CO; ++c) acc[c] = 0.f;

    const float* xb = msa + (((size_t)b * CIN) * H_ + h0) * W_ + w;

#pragma unroll 2
    for (int h = 0; h < 4; ++h) {
        float x[CIN];
#pragma unroll
        for (int i = 0; i < CIN; ++i)
            x[i] = xb[(size_t)i * (H_ * W_) + (size_t)h * W_];
#pragma unroll
        for (int cg = 0; cg < 8; ++cg) {
            float t[8];
#pragma unroll
            for (int c = 0; c < 8; ++c) t[c] = bias[cg * 8 + c];     // uniform -> SGPR
#pragma unroll
            for (int i = 0; i < CIN; ++i) {
#pragma unroll
                for (int c = 0; c < 8; ++c)
                    t[c] = fmaf(Wc[(cg * 8 + c) * CIN + i], x[i], t[c]);  // s_load weight
            }
#pragma unroll
            for (int c = 0; c < 8; ++c) acc[cg * 8 + c] += fmaxf(t[c], 0.f);
        }
    }

    // Cross-wave reduction. float4 slots XOR-swizzled so both the b128 writes
    // (each lane streams its 256B row) and the reads (wave reads one row) hit
    // all 8 bank-groups evenly.
    __shared__ float red[4][64][64];      // 64 KiB -> 2 blocks/CU
    f32x4* rrow = (f32x4*)&red[wv][lane][0];
#pragma unroll
    for (int q = 0; q < 16; ++q) {
        f32x4 v;
        v.x = acc[q * 4 + 0]; v.y = acc[q * 4 + 1];
        v.z = acc[q * 4 + 2]; v.w = acc[q * 4 + 3];
        rrow[q ^ (lane & 15)] = v;
    }
    __syncthreads();

    float* dst = partial + (((size_t)hc * B_ + b) * W_ + wq * 64) * CO;
#pragma unroll
    for (int k = 0; k < 16; ++k) {
        const int flat = k * 256 + tid;   // 0..4095 ; per-wave: one l-row, c=lane
        const int l = flat >> 6, c = flat & 63;
        const int cs = ((((c >> 2) ^ (l & 15)) << 2) | (c & 3));
        dst[flat] = red[0][l][cs] + red[1][l][cs] + red[2][l][cs] + red[3][l][cs];
    }
}

// ---------------------------------------------------------------------------
// Kernel B: avg[b][w][c] = (1/H) * sum_hc partial[hc][b][w][c]
// ---------------------------------------------------------------------------
__global__ __launch_bounds__(256) void reduce_avg_kernel(
    const float* __restrict__ partial,  // [HC][B][W][CO]
    float* __restrict__ avg)            // [B][W][CO]
{
    const int idx = blockIdx.x * 256 + threadIdx.x;   // 0 .. NPART-1
    float s = 0.f;
#pragma unroll
    for (int k = 0; k < HC; ++k) s += partial[(size_t)k * NPART + idx];
    avg[idx] = s * (1.0f / H_);
}

// ---------------------------------------------------------------------------
// Kernel C: out[b][wi][wj][c] = avg[b][wi][c] + avg[b][wj][c]
// Grid (wi=512, b=4) x 256 thr; each wave stores 1 KiB contiguous per iter.
// ---------------------------------------------------------------------------
__global__ __launch_bounds__(256) void pairs_kernel(
    const float* __restrict__ avg,  // [B][W][CO]
    float* __restrict__ out)        // [B][W][W][CO]
{
    const int b   = blockIdx.y;
    const int wi  = blockIdx.x;
    const int tid = threadIdx.x;
    const int cq  = tid & 15;   // c-quad (64 c = 16 float4)
    const int wj0 = tid >> 4;   // 0..15

    const f32x4* a4 = (const f32x4*)avg;
    const f32x4 aI = a4[(b * W_ + wi) * 16 + cq];
    f32x4* o4 = (f32x4*)out + ((size_t)(b * W_ + wi)) * W_ * 16;

#pragma unroll 4
    for (int wj = wj0; wj < W_; wj += 16) {
        const f32x4 aJ = a4[(b * W_ + wj) * 16 + cq];
        const f32x4 r = aI + aJ;
        __builtin_nontemporal_store(r, o4 + (size_t)wj * 16 + cq);
    }
}

extern "C" void kernel_launch(void* const* d_in, const int* in_sizes, int n_in,
                              void* d_out, int out_size, void* d_ws, size_t ws_size,
                              hipStream_t stream) {
    const float* msa = (const float*)d_in[0];   // (4, 23, 256, 512)
    const float* Wc  = (const float*)d_in[1];   // (64, 23)
    const float* bc  = (const float*)d_in[2];   // (64,)
    float* out = (float*)d_out;                 // (4, 512, 512, 64)
    float* avg = (float*)d_ws;                  // (4, 512, 64) = 512 KB scratch

    // Stage partials in d_out: 8 MiB used as dead scratch, fully overwritten
    // by pairs_kernel afterwards (stream-ordered).
    float* partial = (float*)d_out;

    conv_partial_kernel<<<dim3(8, HC, B_), 256, 0, stream>>>(msa, Wc, bc, partial);
    reduce_avg_kernel<<<dim3(NPART / 256), 256, 0, stream>>>(partial, avg);
    pairs_kernel<<<dim3(W_, B_), 256, 0, stream>>>(avg, out);
}

// Round 5
// 229.562 us; speedup vs baseline: 2.4559x; 2.4559x over previous
//
#include <hip/hip_runtime.h>

#define B_   4
#define CIN  23
#define H_   256
#define W_   512
#define CO   64
#define HC   16                 // h-chunks (blocks along H)
#define NPART (B_ * W_ * CO)    // elements per h-chunk partial = 131072

typedef float f32x4 __attribute__((ext_vector_type(4)));

// ---------------------------------------------------------------------------
// Kernel A: 1x1 conv (23->64) + bias + relu, partial sum over a 16-h chunk.
// Grid (wq=8, hc=16, b=4) = 512 blocks x 512 thr (8 waves).
// Wave wv owns channels [8wv, 8wv+8): cg forced to SGPR via readfirstlane so
// every weight/bias access is a scalar-cache s_load (no LDS, no vector loads).
// Lane = w. msa read once from HBM; 8-way cross-wave re-read served by L1.
// partial[hc][b][w][c] staged in d_out (dead scratch, overwritten by pairs).
// ---------------------------------------------------------------------------
__global__ __launch_bounds__(512) void conv_partial_kernel(
    const float* __restrict__ msa,   // [B][CIN][H][W]
    const float* __restrict__ Wc,    // [CO][CIN]
    const float* __restrict__ bias,  // [CO]
    float* __restrict__ partial)     // [HC][B][W][CO]
{
    const int tid  = threadIdx.x;
    const int lane = tid & 63;
    const int cg   = __builtin_amdgcn_readfirstlane(tid >> 6);  // 0..7, SGPR
    const int wq   = blockIdx.x;          // 0..7
    const int hc   = blockIdx.y;          // 0..15
    const int b    = blockIdx.z;
    const int w    = wq * 64 + lane;
    const int h0   = hc * 16;

    const float* Wrow = Wc + cg * 8 * CIN;   // uniform pointer -> s_load

    float bs[8];
#pragma unroll
    for (int c = 0; c < 8; ++c) bs[c] = bias[cg * 8 + c];

    float acc[8];
#pragma unroll
    for (int c = 0; c < 8; ++c) acc[c] = 0.f;

    const float* xb = msa + (((size_t)b * CIN) * H_ + h0) * W_ + w;

#pragma unroll 2
    for (int h = 0; h < 16; ++h) {
        float x[CIN];
#pragma unroll
        for (int i = 0; i < CIN; ++i)
            x[i] = xb[(size_t)i * (H_ * W_) + (size_t)h * W_];

        float t[8];
#pragma unroll
        for (int c = 0; c < 8; ++c) t[c] = bs[c];
#pragma unroll
        for (int i = 0; i < CIN; ++i) {
#pragma unroll
            for (int c = 0; c < 8; ++c)
                t[c] = fmaf(Wrow[c * CIN + i], x[i], t[c]);  // v_fmac v,s,v
        }
#pragma unroll
        for (int c = 0; c < 8; ++c) acc[c] += fmaxf(t[c], 0.f);
    }

    // per-lane 8 consecutive floats; wave writes 2 KB contiguous
    float* dst = partial + ((((size_t)hc * B_ + b) * W_ + w) * CO) + cg * 8;
    f32x4 v0, v1;
    v0.x = acc[0]; v0.y = acc[1]; v0.z = acc[2]; v0.w = acc[3];
    v1.x = acc[4]; v1.y = acc[5]; v1.z = acc[6]; v1.w = acc[7];
    *(f32x4*)(dst)     = v0;
    *(f32x4*)(dst + 4) = v1;
}

// ---------------------------------------------------------------------------
// Kernel B: avg[b][w][c] = (1/H) * sum_hc partial[hc][b][w][c]   (float4-wide)
// ---------------------------------------------------------------------------
__global__ __launch_bounds__(256) void reduce_avg_kernel(
    const float* __restrict__ partial,  // [HC][B][W][CO]
    float* __restrict__ avg)            // [B][W][CO]
{
    const int idx = blockIdx.x * 256 + threadIdx.x;   // f32x4 index, 0..32767
    const f32x4* p4 = (const f32x4*)partial;
    f32x4 s = p4[idx];
#pragma unroll
    for (int k = 1; k < HC; ++k) s += p4[(size_t)k * (NPART / 4) + idx];
    ((f32x4*)avg)[idx] = s * (1.0f / H_);
}

// ---------------------------------------------------------------------------
// Kernel C: out[b][wi][wj][c] = avg[b][wi][c] + avg[b][wj][c]
// Grid (wi=512, b=4) x 256 thr; each wave stores 1 KiB contiguous per iter.
// ---------------------------------------------------------------------------
__global__ __launch_bounds__(256) void pairs_kernel(
    const float* __restrict__ avg,  // [B][W][CO]
    float* __restrict__ out)        // [B][W][W][CO]
{
    const int b   = blockIdx.y;
    const int wi  = blockIdx.x;
    const int tid = threadIdx.x;
    const int cq  = tid & 15;   // c-quad (64 c = 16 float4)
    const int wj0 = tid >> 4;   // 0..15

    const f32x4* a4 = (const f32x4*)avg;
    const f32x4 aI = a4[(b * W_ + wi) * 16 + cq];
    f32x4* o4 = (f32x4*)out + ((size_t)(b * W_ + wi)) * W_ * 16;

#pragma unroll 4
    for (int wj = wj0; wj < W_; wj += 16) {
        const f32x4 aJ = a4[(b * W_ + wj) * 16 + cq];
        const f32x4 r = aI + aJ;
        __builtin_nontemporal_store(r, o4 + (size_t)wj * 16 + cq);
    }
}

extern "C" void kernel_launch(void* const* d_in, const int* in_sizes, int n_in,
                              void* d_out, int out_size, void* d_ws, size_t ws_size,
                              hipStream_t stream) {
    const float* msa = (const float*)d_in[0];   // (4, 23, 256, 512)
    const float* Wc  = (const float*)d_in[1];   // (64, 23)
    const float* bc  = (const float*)d_in[2];   // (64,)
    float* out = (float*)d_out;                 // (4, 512, 512, 64)
    float* avg = (float*)d_ws;                  // (4, 512, 64) = 512 KB scratch

    // Stage partials in d_out: 8 MiB of dead scratch, fully overwritten by
    // pairs_kernel afterwards (stream-ordered: A -> B -> C).
    float* partial = (float*)d_out;

    conv_partial_kernel<<<dim3(8, HC, B_), 512, 0, stream>>>(msa, Wc, bc, partial);
    reduce_avg_kernel<<<dim3(NPART / 4 / 256), 256, 0, stream>>>(partial, avg);
    pairs_kernel<<<dim3(W_, B_), 256, 0, stream>>>(avg, out);
}

// Round 6
// 105.681 us; speedup vs baseline: 5.3346x; 2.1722x over previous
//
#include <hip/hip_runtime.h>

#define B_   4
#define CIN  23
#define H_   256
#define W_   512
#define CO   64

typedef float f32x4 __attribute__((ext_vector_type(4)));

// ---------------------------------------------------------------------------
// Kernel 1: 1x1 conv (23->64) + bias + relu, mean over H -> avg[B][W][CO].
// 512 blocks x 512 thr (8 waves = 4/SIMD, 2 blocks/CU -> all co-resident).
// Block tile: 64 w (lane = w) x 4 channels x full H (wave = 32 h).
// 4 channels/block = 92 weights, provably block-uniform (from blockIdx) ->
// scalar-pipe s_loads, zero LDS / zero vector loads in the inner loop.
//
// XCD-aware block mapping: the 16 channel-group blocks of one (wq,b) msa
// tile are given block ids congruent mod 8 (round-robin XCD assignment) so
// they share one XCD's L2: the 16x msa re-read is L2-served (~34 TB/s agg)
// instead of L3-served (~11 TB/s).
//   bid = r + 8*q ; tile = r + 8*(q>>4) ; cg = q&15 ; tile = wq + 8*b
// ---------------------------------------------------------------------------
__global__ __launch_bounds__(512) void conv_mean_kernel(
    const float* __restrict__ msa,   // [B][CIN][H][W]
    const float* __restrict__ Wc,    // [CO][CIN]
    const float* __restrict__ bias,  // [CO]
    float* __restrict__ avg)         // [B][W][CO]
{
    const int bid  = blockIdx.x;
    const int r    = bid & 7;
    const int q    = bid >> 3;            // 0..63
    const int tile = r + 8 * (q >> 4);    // 0..31 : 16 blocks share a tile+XCD
    const int c0   = (q & 15) * 4;        // channel group (block-uniform)
    const int wq   = tile & 7;
    const int b    = tile >> 3;

    const int tid  = threadIdx.x;
    const int lane = tid & 63;
    const int wv   = tid >> 6;            // 0..7 : h-chunk
    const int w    = wq * 64 + lane;
    const int h0   = wv * 32;

    // uniform bias -> SGPRs
    const float bs0 = bias[c0 + 0], bs1 = bias[c0 + 1];
    const float bs2 = bias[c0 + 2], bs3 = bias[c0 + 3];

    float sum0 = 0.f, sum1 = 0.f, sum2 = 0.f, sum3 = 0.f;

    const float* xb = msa + (((size_t)b * CIN) * H_ + h0) * W_ + w;

    for (int hb = 0; hb < 8; ++hb) {       // 4 h per iteration
        float t0[4], t1[4], t2[4], t3[4];  // [hsub] x 4 channels
        t0[0] = bs0; t0[1] = bs1; t0[2] = bs2; t0[3] = bs3;
        t1[0] = bs0; t1[1] = bs1; t1[2] = bs2; t1[3] = bs3;
        t2[0] = bs0; t2[1] = bs1; t2[2] = bs2; t2[3] = bs3;
        t3[0] = bs0; t3[1] = bs1; t3[2] = bs2; t3[3] = bs3;

        const float* xp = xb + hb * 4 * W_;
#pragma unroll
        for (int i = 0; i < CIN; ++i) {
            const float x0 = xp[0];
            const float x1 = xp[W_];
            const float x2 = xp[2 * W_];
            const float x3 = xp[3 * W_];
            xp += (size_t)H_ * W_;
            // block-uniform weight reads -> s_load; FMA is v_fmac(v, s, v)
            const float wk0 = Wc[(c0 + 0) * CIN + i];
            const float wk1 = Wc[(c0 + 1) * CIN + i];
            const float wk2 = Wc[(c0 + 2) * CIN + i];
            const float wk3 = Wc[(c0 + 3) * CIN + i];
            t0[0] = fmaf(wk0, x0, t0[0]); t0[1] = fmaf(wk1, x0, t0[1]);
            t0[2] = fmaf(wk2, x0, t0[2]); t0[3] = fmaf(wk3, x0, t0[3]);
            t1[0] = fmaf(wk0, x1, t1[0]); t1[1] = fmaf(wk1, x1, t1[1]);
            t1[2] = fmaf(wk2, x1, t1[2]); t1[3] = fmaf(wk3, x1, t1[3]);
            t2[0] = fmaf(wk0, x2, t2[0]); t2[1] = fmaf(wk1, x2, t2[1]);
            t2[2] = fmaf(wk2, x2, t2[2]); t2[3] = fmaf(wk3, x2, t2[3]);
            t3[0] = fmaf(wk0, x3, t3[0]); t3[1] = fmaf(wk1, x3, t3[1]);
            t3[2] = fmaf(wk2, x3, t3[2]); t3[3] = fmaf(wk3, x3, t3[3]);
        }
        sum0 += fmaxf(t0[0], 0.f) + fmaxf(t1[0], 0.f) + fmaxf(t2[0], 0.f) + fmaxf(t3[0], 0.f);
        sum1 += fmaxf(t0[1], 0.f) + fmaxf(t1[1], 0.f) + fmaxf(t2[1], 0.f) + fmaxf(t3[1], 0.f);
        sum2 += fmaxf(t0[2], 0.f) + fmaxf(t1[2], 0.f) + fmaxf(t2[2], 0.f) + fmaxf(t3[2], 0.f);
        sum3 += fmaxf(t0[3], 0.f) + fmaxf(t1[3], 0.f) + fmaxf(t2[3], 0.f) + fmaxf(t3[3], 0.f);
    }

    // cross-wave reduction (8 partials per output), no atomics
    __shared__ float red[8][64][4];        // 8 KiB
    red[wv][lane][0] = sum0;
    red[wv][lane][1] = sum1;
    red[wv][lane][2] = sum2;
    red[wv][lane][3] = sum3;
    __syncthreads();

    if (tid < 256) {
        const int l = tid >> 2;            // w-lane
        const int c = tid & 3;             // channel
        float s = 0.f;
#pragma unroll
        for (int k = 0; k < 8; ++k) s += red[k][l][c];
        avg[((size_t)(b * W_ + wq * 64 + l)) * CO + c0 + c] = s * (1.0f / H_);
    }
}

// ---------------------------------------------------------------------------
// Kernel 2: out[b][wi][wj][c] = avg[b][wi][c] + avg[b][wj][c]
// Grid (wi=512, b=4) x 256 thr; each wave stores 1 KiB contiguous per iter.
// avg (512 KB) is L2-resident; output stream uses nontemporal stores.
// ---------------------------------------------------------------------------
__global__ __launch_bounds__(256) void pairs_kernel(
    const float* __restrict__ avg,  // [B][W][CO]
    float* __restrict__ out)        // [B][W][W][CO]
{
    const int b   = blockIdx.y;
    const int wi  = blockIdx.x;
    const int tid = threadIdx.x;
    const int cq  = tid & 15;   // c-quad (64 c = 16 float4)
    const int wj0 = tid >> 4;   // 0..15

    const f32x4* a4 = (const f32x4*)avg;
    const f32x4 aI = a4[(b * W_ + wi) * 16 + cq];
    f32x4* o4 = (f32x4*)out + ((size_t)(b * W_ + wi)) * W_ * 16;

#pragma unroll 4
    for (int wj = wj0; wj < W_; wj += 16) {
        const f32x4 aJ = a4[(b * W_ + wj) * 16 + cq];
        const f32x4 r = aI + aJ;
        __builtin_nontemporal_store(r, o4 + (size_t)wj * 16 + cq);
    }
}

extern "C" void kernel_launch(void* const* d_in, const int* in_sizes, int n_in,
                              void* d_out, int out_size, void* d_ws, size_t ws_size,
                              hipStream_t stream) {
    const float* msa = (const float*)d_in[0];   // (4, 23, 256, 512)
    const float* Wc  = (const float*)d_in[1];   // (64, 23)
    const float* bc  = (const float*)d_in[2];   // (64,)
    float* out = (float*)d_out;                 // (4, 512, 512, 64)
    float* avg = (float*)d_ws;                  // (4, 512, 64) scratch, fully overwritten

    conv_mean_kernel<<<dim3(512), 512, 0, stream>>>(msa, Wc, bc, avg);
    pairs_kernel<<<dim3(W_, B_), 256, 0, stream>>>(avg, out);
}